// Round 2
// baseline (15957.077 us; speedup 1.0000x reference)
//
#include <hip/hip_runtime.h>
#include <math.h>

#define Sx 128
#define Bx 1024
#define EMBx 256
#define Mx 3
#define KXx 115            // reduced width = 40+40+35
#define KTOTx 371          // 115 + 256
#define RSTR 120           // padded reduced row stride (480 B, 16B-aligned)
#define TAUx 5.0f
#define DEC_SZ (Sx * Mx * Bx)  // 393216

// ============================ prep ============================
// Wt3[k][dd][q] (k<384, dd<256, q<4), gate col j = q*256+dd:
//   k<115    -> W_ih[j][k]
//   115..370 -> W_hh[j][k-115] + sum_p W_ih[j][115+p] * W_dec[p][k-115]  (prev-logits folded)
//   else 0
// WTA[k][tx][q] (k<304): col c=q*16+tx : (c<40 && k<300) ? W0[c][k] : 0
// WTB[k][tx][q] (k<76):  (c<40 && k<74) ? W1[c][k] : 0
// bias0[j] = b_ih+b_hh ; bias2[j] = bias0 + sum_p W_ih[j][115+p]*b_dec[p]
__global__ __launch_bounds__(256) void k_prep(
    const float* __restrict__ W0, const float* __restrict__ W1,
    const float* __restrict__ W_ih, const float* __restrict__ W_hh,
    const float* __restrict__ W_dec, const float* __restrict__ b_ih,
    const float* __restrict__ b_hh, const float* __restrict__ b_dec,
    float* __restrict__ Wt3, float* __restrict__ WTA, float* __restrict__ WTB,
    float* __restrict__ bias0, float* __restrict__ bias2) {
  int idx = blockIdx.x * 256 + threadIdx.x;
  if (idx < 384 * 1024) {
    int k = idx >> 10, rem = idx & 1023;
    int dd = rem >> 2, q = rem & 3;
    int j = q * 256 + dd;
    float v = 0.f;
    if (k < KXx) {
      v = W_ih[j * 121 + k];
    } else if (k < KTOTx) {
      int kh = k - KXx;
      v = W_hh[j * 256 + kh];
#pragma unroll
      for (int p = 0; p < 6; ++p)
        v = fmaf(W_ih[j * 121 + 115 + p], W_dec[p * 256 + kh], v);
    }
    Wt3[idx] = v;
    return;
  }
  int r1 = idx - 384 * 1024;
  if (r1 < 304 * 64) {
    int k = r1 >> 6, rem = r1 & 63;
    int txx = rem >> 2, q = rem & 3, c = q * 16 + txx;
    WTA[r1] = (c < 40 && k < 300) ? W0[c * 300 + k] : 0.f;
    return;
  }
  int r2 = r1 - 304 * 64;
  if (r2 < 76 * 64) {
    int k = r2 >> 6, rem = r2 & 63;
    int txx = rem >> 2, q = rem & 3, c = q * 16 + txx;
    WTB[r2] = (c < 40 && k < 74) ? W1[c * 74 + k] : 0.f;
    return;
  }
  int r3 = r2 - 76 * 64;
  if (r3 < 1024) {
    int j = r3;
    float b = b_ih[j] + b_hh[j];
    bias0[j] = b;
    float b2 = b;
#pragma unroll
    for (int p = 0; p < 6; ++p) b2 = fmaf(W_ih[j * 121 + 115 + p], b_dec[p], b2);
    bias2[j] = b2;
  }
}

// ============================ input projections ============================
// MODE 0: reduced[:, 0:40]  = x0 @ W0^T + b0   (K padded 304)
// MODE 1: reduced[:, 40:80] = x1 @ W1^T + b1   (K padded 76); also copies x2 -> cols 80:114, zeros 115:119
// Block: 64 rows. Weights AND x-tile fully in LDS; inner loop is pure LDS+FMA.
template <int MODE>
__global__ __launch_bounds__(512) void k_in(const float* __restrict__ X,
                                            const float* __restrict__ x2,
                                            const float* __restrict__ WT,
                                            const float* __restrict__ bias,
                                            float* __restrict__ red) {
  constexpr int KD = (MODE == 0) ? 300 : 74;
  constexpr int KP = (MODE == 0) ? 304 : 76;
  constexpr int OFF = (MODE == 0) ? 0 : 40;
  __shared__ __align__(16) float xs[64][KP];
  __shared__ __align__(16) float wl[KP * 64];

  int r0 = blockIdx.x * 64;
  int tid = threadIdx.x, tx = tid & 15, ty = tid >> 4;

  for (int i = tid; i < 64 * KP; i += 512) {
    int r = i / KP, k = i - r * KP;
    xs[r][k] = (k < KD) ? X[(size_t)(r0 + r) * KD + k] : 0.f;
  }
  for (int i = tid; i < KP * 64; i += 512) wl[i] = WT[i];
  __syncthreads();

  float acc[2][4] = {{0.f, 0.f, 0.f, 0.f}, {0.f, 0.f, 0.f, 0.f}};
#pragma unroll 4
  for (int kk = 0; kk < KP; kk += 4) {
    float4 w0 = *(const float4*)&wl[(kk + 0) * 64 + tx * 4];
    float4 w1 = *(const float4*)&wl[(kk + 1) * 64 + tx * 4];
    float4 w2 = *(const float4*)&wl[(kk + 2) * 64 + tx * 4];
    float4 w3 = *(const float4*)&wl[(kk + 3) * 64 + tx * 4];
#pragma unroll
    for (int rr = 0; rr < 2; ++rr) {
      float4 xv = *(const float4*)&xs[ty * 2 + rr][kk];
      acc[rr][0] = fmaf(xv.x, w0.x, acc[rr][0]);
      acc[rr][1] = fmaf(xv.x, w0.y, acc[rr][1]);
      acc[rr][2] = fmaf(xv.x, w0.z, acc[rr][2]);
      acc[rr][3] = fmaf(xv.x, w0.w, acc[rr][3]);
      acc[rr][0] = fmaf(xv.y, w1.x, acc[rr][0]);
      acc[rr][1] = fmaf(xv.y, w1.y, acc[rr][1]);
      acc[rr][2] = fmaf(xv.y, w1.z, acc[rr][2]);
      acc[rr][3] = fmaf(xv.y, w1.w, acc[rr][3]);
      acc[rr][0] = fmaf(xv.z, w2.x, acc[rr][0]);
      acc[rr][1] = fmaf(xv.z, w2.y, acc[rr][1]);
      acc[rr][2] = fmaf(xv.z, w2.z, acc[rr][2]);
      acc[rr][3] = fmaf(xv.z, w2.w, acc[rr][3]);
      acc[rr][0] = fmaf(xv.w, w3.x, acc[rr][0]);
      acc[rr][1] = fmaf(xv.w, w3.y, acc[rr][1]);
      acc[rr][2] = fmaf(xv.w, w3.z, acc[rr][2]);
      acc[rr][3] = fmaf(xv.w, w3.w, acc[rr][3]);
    }
  }
#pragma unroll
  for (int rr = 0; rr < 2; ++rr) {
    int row = r0 + ty * 2 + rr;
#pragma unroll
    for (int q = 0; q < 4; ++q) {
      int c = q * 16 + tx;
      if (c < 40) red[(size_t)row * RSTR + OFF + c] = acc[rr][q] + bias[c];
    }
  }
  if constexpr (MODE == 1) {
    for (int i = tid; i < 64 * 40; i += 512) {
      int r = i / 40, c = i - r * 40;
      red[(size_t)(r0 + r) * RSTR + 80 + c] =
          (c < 35) ? x2[(size_t)(r0 + r) * 35 + c] : 0.f;
    }
  }
}

// ============================ persistent LSTM ============================
__device__ __forceinline__ void stage(float (*dst)[96], const float* __restrict__ redt,
                                      const float* __restrict__ hprev, int kbase,
                                      int r0, int tid) {
  for (int i = tid; i < 64 * 96; i += 512) {
    int r = i / 96, kk = i - r * 96, k = kbase + kk;
    float v = 0.f;
    if (k < KXx)
      v = redt[(size_t)(r0 + r) * RSTR + k];
    else if (k < KTOTx && hprev)
      v = hprev[(size_t)(r0 + r) * EMBx + (k - KXx)];
    dst[r][kk] = v;
  }
}

template <int NQ>
__device__ __forceinline__ void compute(float (&acc)[2][4], const float (*xb)[96],
                                        const float* __restrict__ wl, int kbase,
                                        int tx, int ty) {
#pragma unroll 8
  for (int kk = 0; kk < NQ; ++kk) {
    int k = kbase + kk * 4;
    float4 w0 = *(const float4*)&wl[(k + 0) * 64 + tx * 4];
    float4 w1 = *(const float4*)&wl[(k + 1) * 64 + tx * 4];
    float4 w2 = *(const float4*)&wl[(k + 2) * 64 + tx * 4];
    float4 w3 = *(const float4*)&wl[(k + 3) * 64 + tx * 4];
#pragma unroll
    for (int rr = 0; rr < 2; ++rr) {
      float4 xv = *(const float4*)&xb[ty * 2 + rr][kk * 4];
      acc[rr][0] = fmaf(xv.x, w0.x, acc[rr][0]);
      acc[rr][1] = fmaf(xv.x, w0.y, acc[rr][1]);
      acc[rr][2] = fmaf(xv.x, w0.z, acc[rr][2]);
      acc[rr][3] = fmaf(xv.x, w0.w, acc[rr][3]);
      acc[rr][0] = fmaf(xv.y, w1.x, acc[rr][0]);
      acc[rr][1] = fmaf(xv.y, w1.y, acc[rr][1]);
      acc[rr][2] = fmaf(xv.y, w1.z, acc[rr][2]);
      acc[rr][3] = fmaf(xv.y, w1.w, acc[rr][3]);
      acc[rr][0] = fmaf(xv.z, w2.x, acc[rr][0]);
      acc[rr][1] = fmaf(xv.z, w2.y, acc[rr][1]);
      acc[rr][2] = fmaf(xv.z, w2.z, acc[rr][2]);
      acc[rr][3] = fmaf(xv.z, w2.w, acc[rr][3]);
      acc[rr][0] = fmaf(xv.w, w3.x, acc[rr][0]);
      acc[rr][1] = fmaf(xv.w, w3.y, acc[rr][1]);
      acc[rr][2] = fmaf(xv.w, w3.z, acc[rr][2]);
      acc[rr][3] = fmaf(xv.w, w3.w, acc[rr][3]);
    }
  }
}

// grid 256 = 16 groups (row-tiles of 64) x 16 col-tiles (16 gate-dims each).
// Groups are CONTIGUOUS in blockIdx (deadlock-safe under partial residency:
// any 16 consecutively-dispatched blocks can complete as a group).
// 1 block/CU (LDS 141 KB) -> all 256 resident on 256 CUs.
__global__ __launch_bounds__(512, 2) void k_lstm(
    const float* __restrict__ red, const float* __restrict__ Wt3,
    const float* __restrict__ bias0, const float* __restrict__ bias2,
    const float* __restrict__ W_dec, const float* __restrict__ b_dec,
    const float* __restrict__ gu, float* __restrict__ hbuf,
    int* __restrict__ bar, float* __restrict__ outp) {
  __shared__ __align__(16) float wl[372 * 64];      // 95232 B
  __shared__ __align__(16) float xl[2][64][96];     // 49152 B  (total 144384 B)

  int b = blockIdx.x;
  int g = b >> 4, ct = b & 15;
  int r0 = g * 64, d0 = ct * 16;
  int tid = threadIdx.x, tx = tid & 15, ty = tid >> 4;
  int d = d0 + tx;

  // weight slice -> LDS, once
  for (int i = tid; i < 372 * 64; i += 512) {
    int k = i >> 6, j = i & 63;
    wl[i] = Wt3[(size_t)k * 1024 + d0 * 4 + j];
  }
  float b0r[4], b2r[4];
#pragma unroll
  for (int q = 0; q < 4; ++q) {
    b0r[q] = bias0[q * 256 + d];
    b2r[q] = bias2[q * 256 + d];
  }
  float creg[2] = {0.f, 0.f};

  const float* hprev = hbuf;            // zeroed by memset
  float* hcur = hbuf + 262144;

  stage(xl[0], red, nullptr, 0, r0, tid);   // chunk0 of t=0 (k<96 -> reduced only)
  __syncthreads();

  for (int t = 0; t < Sx; ++t) {
    const float* redt = red + (size_t)t * Bx * RSTR;
    float acc[2][4] = {{0.f, 0.f, 0.f, 0.f}, {0.f, 0.f, 0.f, 0.f}};

    stage(xl[1], redt, hprev, 96, r0, tid);
    compute<24>(acc, xl[0], wl, 0, tx, ty);
    __syncthreads();
    stage(xl[0], redt, hprev, 192, r0, tid);
    compute<24>(acc, xl[1], wl, 96, tx, ty);
    __syncthreads();
    stage(xl[1], redt, hprev, 288, r0, tid);
    compute<24>(acc, xl[0], wl, 192, tx, ty);
    __syncthreads();
    if (t < Sx - 1)
      stage(xl[0], red + (size_t)(t + 1) * Bx * RSTR, nullptr, 0, r0, tid);
    compute<21>(acc, xl[1], wl, 288, tx, ty);

    // LSTM pointwise; c stays in registers
#pragma unroll
    for (int rr = 0; rr < 2; ++rr) {
      int row = r0 + ty * 2 + rr;
      float iv = acc[rr][0] + ((t == 0) ? b0r[0] : b2r[0]);
      float fv = acc[rr][1] + ((t == 0) ? b0r[1] : b2r[1]);
      float gv = acc[rr][2] + ((t == 0) ? b0r[2] : b2r[2]);
      float ov = acc[rr][3] + ((t == 0) ? b0r[3] : b2r[3]);
      float si = 1.f / (1.f + expf(-iv));
      float sf = 1.f / (1.f + expf(-fv));
      float so = 1.f / (1.f + expf(-ov));
      float tg = tanhf(gv);
      float cn = __fadd_rn(__fmul_rn(sf, creg[rr]), __fmul_rn(si, tg));
      creg[rr] = cn;
      hcur[(size_t)row * EMBx + d] = __fmul_rn(so, tanhf(cn));
    }

    // publish h_t, group barrier
    __threadfence();
    __syncthreads();
    if (tid == 0) {
      atomicAdd(bar + g, 1);
      while (__hip_atomic_load(bar + g, __ATOMIC_ACQUIRE,
                               __HIP_MEMORY_SCOPE_AGENT) < 16 * (t + 1))
        __builtin_amdgcn_s_sleep(2);
    }
    __syncthreads();
    __threadfence();  // invalidate L1 so cross-block h reads are fresh

    // logits + gumbel decisions for this step (4 rows per block)
    {
      int grp = tid >> 4, lane = tid & 15;
      if (grp < 24) {
        int r = grp / 6, p = grp - r * 6;
        int row = r0 + ct * 4 + r;
        const float* hr = hcur + (size_t)row * EMBx + lane * 16;
        const float* wd = W_dec + p * EMBx + lane * 16;
        float s = 0.f;
#pragma unroll
        for (int jj = 0; jj < 4; ++jj) {
          float4 hv = *(const float4*)(hr + jj * 4);
          float4 wv = *(const float4*)(wd + jj * 4);
          s += hv.x * wv.x + hv.y * wv.y + hv.z * wv.z + hv.w * wv.w;
        }
        s += __shfl_xor(s, 1);
        s += __shfl_xor(s, 2);
        s += __shfl_xor(s, 4);
        s += __shfl_xor(s, 8);
        float logit = s + b_dec[p];
        int m = p >> 1, o = p & 1;
        if (lane == 0)
          outp[DEC_SZ + (((size_t)(t * Mx + m) * Bx + row) << 1) + o] = logit;
        float other = __shfl_xor(logit, 16);  // partner gate-col (same m, other o)
        if (lane == 0 && o == 0) {
          const float* up = gu + (((size_t)t * 3072 + m * 1024 + row) << 1);
          float g0 = -logf(-logf(up[0]));
          float g1 = -logf(-logf(up[1]));
          float v0 = (logit + g0) / TAUx;
          float v1 = (other + g1) / TAUx;
          outp[(size_t)t * 3072 + m * 1024 + row] = (v1 > v0) ? 1.0f : 0.0f;
        }
      }
    }

    float* tmp = (float*)hprev;
    hprev = hcur;
    hcur = (t & 1) ? hbuf + 262144 : hbuf;  // ping-pong
  }
}

extern "C" void kernel_launch(void* const* d_in, const int* in_sizes, int n_in,
                              void* d_out, int out_size, void* d_ws, size_t ws_size,
                              hipStream_t stream) {
  const float* x0 = (const float*)d_in[0];
  const float* x1 = (const float*)d_in[1];
  const float* x2 = (const float*)d_in[2];
  const float* gu = (const float*)d_in[4];
  const float* W0 = (const float*)d_in[5];
  const float* b0 = (const float*)d_in[6];
  const float* W1 = (const float*)d_in[7];
  const float* b1 = (const float*)d_in[8];
  const float* W_ih = (const float*)d_in[9];
  const float* W_hh = (const float*)d_in[10];
  const float* b_ih = (const float*)d_in[11];
  const float* b_hh = (const float*)d_in[12];
  const float* W_dec = (const float*)d_in[13];
  const float* b_dec = (const float*)d_in[14];
  float* outp = (float*)d_out;

  float* ws = (float*)d_ws;
  float* Wt3 = ws;                      // 384*1024 = 393216
  float* WTA = Wt3 + 393216;            // 304*64   = 19456
  float* WTB = WTA + 19456;             // 76*64    = 4864
  float* bias0 = WTB + 4864;            // 1024
  float* bias2 = bias0 + 1024;          // 1024
  int* bar = (int*)(bias2 + 1024);      // 64 ints
  float* hbuf = bias2 + 1024 + 64;      // 2*1024*256 = 524288
  float* reduced = hbuf + 524288;       // 128*1024*120 = 15728640

  hipMemsetAsync(bar, 0, 64 * sizeof(int), stream);
  hipMemsetAsync(hbuf, 0, 262144 * sizeof(float), stream);  // h_{-1} = 0

  k_prep<<<1635, 256, 0, stream>>>(W0, W1, W_ih, W_hh, W_dec, b_ih, b_hh, b_dec,
                                   Wt3, WTA, WTB, bias0, bias2);
  k_in<0><<<2048, 512, 0, stream>>>(x0, nullptr, WTA, b0, reduced);
  k_in<1><<<2048, 512, 0, stream>>>(x1, x2, WTB, b1, reduced);
  k_lstm<<<256, 512, 0, stream>>>(reduced, Wt3, bias0, bias2, W_dec, b_dec, gu,
                                  hbuf, bar, outp);
}

// Round 3
// 6190.335 us; speedup vs baseline: 2.5777x; 2.5777x over previous
//
#include <hip/hip_runtime.h>
#include <math.h>

#define Sx 128
#define Bx 1024
#define EMBx 256
#define Mx 3
#define KXx 115            // reduced width = 40+40+35
#define KTOTx 371          // 256 (h) + 115 (reduced)
#define KPx 384            // padded K: [h 0:256 | reduced 256:371 | zero 371:384]
#define RSTR 120           // padded reduced row stride
#define TAUx 5.0f
#define DEC_SZ (Sx * Mx * Bx)  // 393216
#define Rr 6               // rows per LSTM block
#define NBx 171            // ceil(1024/6)

// ============================ prep ============================
// W4[k*1024 + c] (k<384, c = q*256+dd = gate col):
//   k<256    -> W_hh[c][k] + sum_p W_ih[c][115+p] * W_dec[p][k]   (prev-logits folded)
//   256..370 -> W_ih[c][k-256]
//   else 0
// WTA[k][tx][q] (k<304): col cc=q*16+tx : (cc<40 && k<300) ? W0[cc][k] : 0
// WTB[k][tx][q] (k<76):  (cc<40 && k<74) ? W1[cc][k] : 0
// bias0[c] = b_ih+b_hh ; bias2[c] = bias0 + sum_p W_ih[c][115+p]*b_dec[p]
__global__ __launch_bounds__(256) void k_prep(
    const float* __restrict__ W0, const float* __restrict__ W1,
    const float* __restrict__ W_ih, const float* __restrict__ W_hh,
    const float* __restrict__ W_dec, const float* __restrict__ b_ih,
    const float* __restrict__ b_hh, const float* __restrict__ b_dec,
    float* __restrict__ W4, float* __restrict__ WTA, float* __restrict__ WTB,
    float* __restrict__ bias0, float* __restrict__ bias2) {
  int idx = blockIdx.x * 256 + threadIdx.x;
  if (idx < 384 * 1024) {
    int k = idx >> 10, c = idx & 1023;
    float v = 0.f;
    if (k < 256) {
      v = W_hh[c * 256 + k];
#pragma unroll
      for (int p = 0; p < 6; ++p)
        v = fmaf(W_ih[c * 121 + 115 + p], W_dec[p * 256 + k], v);
    } else if (k < KTOTx) {
      v = W_ih[c * 121 + (k - 256)];
    }
    W4[idx] = v;
    return;
  }
  int r1 = idx - 384 * 1024;
  if (r1 < 304 * 64) {
    int k = r1 >> 6, rem = r1 & 63;
    int txx = rem >> 2, q = rem & 3, cc = q * 16 + txx;
    WTA[r1] = (cc < 40 && k < 300) ? W0[cc * 300 + k] : 0.f;
    return;
  }
  int r2 = r1 - 304 * 64;
  if (r2 < 76 * 64) {
    int k = r2 >> 6, rem = r2 & 63;
    int txx = rem >> 2, q = rem & 3, cc = q * 16 + txx;
    WTB[r2] = (cc < 40 && k < 74) ? W1[cc * 74 + k] : 0.f;
    return;
  }
  int r3 = r2 - 76 * 64;
  if (r3 < 1024) {
    int c = r3;
    float b = b_ih[c] + b_hh[c];
    bias0[c] = b;
    float b2 = b;
#pragma unroll
    for (int p = 0; p < 6; ++p) b2 = fmaf(W_ih[c * 121 + 115 + p], b_dec[p], b2);
    bias2[c] = b2;
  }
}

// ============================ input projections ============================
template <int MODE>
__global__ __launch_bounds__(512) void k_in(const float* __restrict__ X,
                                            const float* __restrict__ x2,
                                            const float* __restrict__ WT,
                                            const float* __restrict__ bias,
                                            float* __restrict__ red) {
  constexpr int KD = (MODE == 0) ? 300 : 74;
  constexpr int KP = (MODE == 0) ? 304 : 76;
  constexpr int OFF = (MODE == 0) ? 0 : 40;
  __shared__ __align__(16) float xs[64][KP];
  __shared__ __align__(16) float wl[KP * 64];

  int r0 = blockIdx.x * 64;
  int tid = threadIdx.x, tx = tid & 15, ty = tid >> 4;

  for (int i = tid; i < 64 * KP; i += 512) {
    int r = i / KP, k = i - r * KP;
    xs[r][k] = (k < KD) ? X[(size_t)(r0 + r) * KD + k] : 0.f;
  }
  for (int i = tid; i < KP * 64; i += 512) wl[i] = WT[i];
  __syncthreads();

  float acc[2][4] = {{0.f, 0.f, 0.f, 0.f}, {0.f, 0.f, 0.f, 0.f}};
#pragma unroll 4
  for (int kk = 0; kk < KP; kk += 4) {
    float4 w0 = *(const float4*)&wl[(kk + 0) * 64 + tx * 4];
    float4 w1 = *(const float4*)&wl[(kk + 1) * 64 + tx * 4];
    float4 w2 = *(const float4*)&wl[(kk + 2) * 64 + tx * 4];
    float4 w3 = *(const float4*)&wl[(kk + 3) * 64 + tx * 4];
#pragma unroll
    for (int rr = 0; rr < 2; ++rr) {
      float4 xv = *(const float4*)&xs[ty * 2 + rr][kk];
      acc[rr][0] = fmaf(xv.x, w0.x, acc[rr][0]);
      acc[rr][1] = fmaf(xv.x, w0.y, acc[rr][1]);
      acc[rr][2] = fmaf(xv.x, w0.z, acc[rr][2]);
      acc[rr][3] = fmaf(xv.x, w0.w, acc[rr][3]);
      acc[rr][0] = fmaf(xv.y, w1.x, acc[rr][0]);
      acc[rr][1] = fmaf(xv.y, w1.y, acc[rr][1]);
      acc[rr][2] = fmaf(xv.y, w1.z, acc[rr][2]);
      acc[rr][3] = fmaf(xv.y, w1.w, acc[rr][3]);
      acc[rr][0] = fmaf(xv.z, w2.x, acc[rr][0]);
      acc[rr][1] = fmaf(xv.z, w2.y, acc[rr][1]);
      acc[rr][2] = fmaf(xv.z, w2.z, acc[rr][2]);
      acc[rr][3] = fmaf(xv.z, w2.w, acc[rr][3]);
      acc[rr][0] = fmaf(xv.w, w3.x, acc[rr][0]);
      acc[rr][1] = fmaf(xv.w, w3.y, acc[rr][1]);
      acc[rr][2] = fmaf(xv.w, w3.z, acc[rr][2]);
      acc[rr][3] = fmaf(xv.w, w3.w, acc[rr][3]);
    }
  }
#pragma unroll
  for (int rr = 0; rr < 2; ++rr) {
    int row = r0 + ty * 2 + rr;
#pragma unroll
    for (int q = 0; q < 4; ++q) {
      int c = q * 16 + tx;
      if (c < 40) red[(size_t)row * RSTR + OFF + c] = acc[rr][q] + bias[c];
    }
  }
  if constexpr (MODE == 1) {
    for (int i = tid; i < 64 * 40; i += 512) {
      int r = i / 40, c = i - r * 40;
      red[(size_t)(r0 + r) * RSTR + 80 + c] =
          (c < 35) ? x2[(size_t)(r0 + r) * 35 + c] : 0.f;
    }
  }
}

// ============================ sync-free LSTM ============================
// Block owns Rr=6 complete batch rows for all 128 steps. h,c never leave the
// block (LDS/registers) -> NO inter-block sync, NO fences, NO atomics.
// 1024 threads = 512 col-pairs x 2 row-groups (3 rows each), thread tile 3x2.
// Weights streamed from L2 (same 1.5MB by all blocks -> L2-resident),
// register double-buffered; x from LDS via uniform-address broadcast reads.

#define FMA_QUAD(W, XPTR0, XPTR1, XPTR2, KOFF)                               \
  {                                                                          \
    float4 xv0 = *(const float4*)((XPTR0) + (KOFF));                         \
    float4 xv1 = *(const float4*)((XPTR1) + (KOFF));                         \
    float4 xv2 = *(const float4*)((XPTR2) + (KOFF));                         \
    acc00 = fmaf(xv0.x, W[0].x, acc00); acc01 = fmaf(xv0.x, W[0].y, acc01);  \
    acc10 = fmaf(xv1.x, W[0].x, acc10); acc11 = fmaf(xv1.x, W[0].y, acc11);  \
    acc20 = fmaf(xv2.x, W[0].x, acc20); acc21 = fmaf(xv2.x, W[0].y, acc21);  \
    acc00 = fmaf(xv0.y, W[1].x, acc00); acc01 = fmaf(xv0.y, W[1].y, acc01);  \
    acc10 = fmaf(xv1.y, W[1].x, acc10); acc11 = fmaf(xv1.y, W[1].y, acc11);  \
    acc20 = fmaf(xv2.y, W[1].x, acc20); acc21 = fmaf(xv2.y, W[1].y, acc21);  \
    acc00 = fmaf(xv0.z, W[2].x, acc00); acc01 = fmaf(xv0.z, W[2].y, acc01);  \
    acc10 = fmaf(xv1.z, W[2].x, acc10); acc11 = fmaf(xv1.z, W[2].y, acc11);  \
    acc20 = fmaf(xv2.z, W[2].x, acc20); acc21 = fmaf(xv2.z, W[2].y, acc21);  \
    acc00 = fmaf(xv0.w, W[3].x, acc00); acc01 = fmaf(xv0.w, W[3].y, acc01);  \
    acc10 = fmaf(xv1.w, W[3].x, acc10); acc11 = fmaf(xv1.w, W[3].y, acc11);  \
    acc20 = fmaf(xv2.w, W[3].x, acc20); acc21 = fmaf(xv2.w, W[3].y, acc21);  \
  }

__global__ __launch_bounds__(1024) void k_lstm(
    const float* __restrict__ red, const float* __restrict__ W4,
    const float* __restrict__ bias0, const float* __restrict__ bias2,
    const float* __restrict__ W_dec, const float* __restrict__ b_dec,
    const float* __restrict__ gu, float* __restrict__ outp) {
  __shared__ __align__(16) float xs[2][Rr][KPx];   // 18432 B
  __shared__ __align__(16) float gl[Rr][1024];     // 24576 B

  const int tid = threadIdx.x;
  const int r0 = blockIdx.x * Rr;
  const int tx = tid & 511, ty = tid >> 9;
  const int lr0 = 3 * ty;

  // ---- init: zero xs (h part of t=0, zero-pad), then stage reduced t=0 ----
  for (int i = tid; i < 2 * Rr * KPx; i += 1024) ((float*)xs)[i] = 0.f;

  // updater-thread setup (elem e1 = tid, e2 = tid+1024 if <1536)
  const int dd = tid & 255;
  const int ur1 = tid >> 8;                 // 0..3
  const int ur2 = ur1 + 4;                  // 4..5 (valid if tid<512)
  float b0v[4], b2v[4];
#pragma unroll
  for (int q = 0; q < 4; ++q) {
    b0v[q] = bias0[q * 256 + dd];
    b2v[q] = bias2[q * 256 + dd];
  }
  float c1 = 0.f, c2 = 0.f;

  // prefetch index for reduced staging
  const int pr_r = (tid < Rr * KXx) ? tid / KXx : 0;
  const int pr_k = (tid < Rr * KXx) ? tid - pr_r * KXx : 0;
  int pr_row = r0 + pr_r;
  if (pr_row > 1023) pr_row = 1023;

  __syncthreads();
  if (tid < Rr * KXx) xs[0][pr_r][256 + pr_k] = red[(size_t)pr_row * RSTR + pr_k];
  __syncthreads();

  const float* wp = W4 + (tx << 1);

  for (int t = 0; t < Sx; ++t) {
    const int cur = t & 1, nxt = cur ^ 1;

    // prefetch next step's reduced slice into a register (covered by GEMM)
    float pf = 0.f;
    if (t < Sx - 1 && tid < Rr * KXx)
      pf = red[(size_t)(t + 1) * Bx * RSTR + (size_t)pr_row * RSTR + pr_k];

    // ---- GEMM: gates[c] = sum_k xs[cur][r][k] * W4[k][c] ----
    const float* xp0 = &xs[cur][lr0 + 0][0];
    const float* xp1 = &xs[cur][lr0 + 1][0];
    const float* xp2 = &xs[cur][lr0 + 2][0];
    float acc00 = 0.f, acc01 = 0.f, acc10 = 0.f, acc11 = 0.f, acc20 = 0.f,
          acc21 = 0.f;
    float2 wa[4], wb[4];
#pragma unroll
    for (int q = 0; q < 4; ++q) wa[q] = *(const float2*)(wp + q * 1024);
    for (int kq = 0; kq < 96; kq += 2) {
      const float* wn = wp + (kq + 1) * 4096;
#pragma unroll
      for (int q = 0; q < 4; ++q) wb[q] = *(const float2*)(wn + q * 1024);
      FMA_QUAD(wa, xp0, xp1, xp2, kq * 4);
      if (kq + 2 < 96) {
        const float* wn2 = wp + (kq + 2) * 4096;
#pragma unroll
        for (int q = 0; q < 4; ++q) wa[q] = *(const float2*)(wn2 + q * 1024);
      }
      FMA_QUAD(wb, xp0, xp1, xp2, kq * 4 + 4);
    }

    // ---- store gates to LDS ----
    *(float2*)&gl[lr0 + 0][tx << 1] = make_float2(acc00, acc01);
    *(float2*)&gl[lr0 + 1][tx << 1] = make_float2(acc10, acc11);
    *(float2*)&gl[lr0 + 2][tx << 1] = make_float2(acc20, acc21);
    __syncthreads();

    // ---- LSTM pointwise update (c in registers), h -> xs[nxt][r][dd] ----
    {
      float bi = (t == 0) ? b0v[0] : b2v[0];
      float bf = (t == 0) ? b0v[1] : b2v[1];
      float bg = (t == 0) ? b0v[2] : b2v[2];
      float bo = (t == 0) ? b0v[3] : b2v[3];
      {
        float iv = gl[ur1][dd] + bi, fv = gl[ur1][256 + dd] + bf;
        float gv = gl[ur1][512 + dd] + bg, ov = gl[ur1][768 + dd] + bo;
        float si = 1.f / (1.f + expf(-iv));
        float sf = 1.f / (1.f + expf(-fv));
        float so = 1.f / (1.f + expf(-ov));
        float tg = tanhf(gv);
        float cn = __fadd_rn(__fmul_rn(sf, c1), __fmul_rn(si, tg));
        c1 = cn;
        xs[nxt][ur1][dd] = __fmul_rn(so, tanhf(cn));
      }
      if (tid < 512) {
        float iv = gl[ur2][dd] + bi, fv = gl[ur2][256 + dd] + bf;
        float gv = gl[ur2][512 + dd] + bg, ov = gl[ur2][768 + dd] + bo;
        float si = 1.f / (1.f + expf(-iv));
        float sf = 1.f / (1.f + expf(-fv));
        float so = 1.f / (1.f + expf(-ov));
        float tg = tanhf(gv);
        float cn = __fadd_rn(__fmul_rn(sf, c2), __fmul_rn(si, tg));
        c2 = cn;
        xs[nxt][ur2][dd] = __fmul_rn(so, tanhf(cn));
      }
    }
    // write prefetched reduced for t+1
    if (t < Sx - 1 && tid < Rr * KXx) xs[nxt][pr_r][256 + pr_k] = pf;
    __syncthreads();

    // ---- logits + gumbel decisions for step t (h = xs[nxt][r][0:256]) ----
    {
      int grp = tid >> 4, lane = tid & 15;
      if (grp < Rr * 6) {
        int r = grp / 6, p = grp - r * 6;
        int row = r0 + r;
        const float* hr = &xs[nxt][r][lane * 16];
        const float* wd = W_dec + p * 256 + lane * 16;
        float s = 0.f;
#pragma unroll
        for (int jj = 0; jj < 4; ++jj) {
          float4 hv = *(const float4*)(hr + jj * 4);
          float4 wv = *(const float4*)(wd + jj * 4);
          s += hv.x * wv.x + hv.y * wv.y + hv.z * wv.z + hv.w * wv.w;
        }
        s += __shfl_xor(s, 1, 64);
        s += __shfl_xor(s, 2, 64);
        s += __shfl_xor(s, 4, 64);
        s += __shfl_xor(s, 8, 64);
        float logit = s + b_dec[p];
        int m = p >> 1, o = p & 1;
        if (lane == 0 && row < 1024)
          outp[DEC_SZ + (((size_t)(t * Mx + m) * Bx + row) << 1) + o] = logit;
        float other = __shfl_xor(logit, 16, 64);  // partner gate (p^1), same lane
        if (lane == 0 && o == 0 && row < 1024) {
          const float* up = gu + (((size_t)t * 3072 + m * 1024 + row) << 1);
          float g0 = -logf(-logf(up[0]));
          float g1 = -logf(-logf(up[1]));
          float v0 = (logit + g0) / TAUx;
          float v1 = (other + g1) / TAUx;
          outp[(size_t)t * 3072 + m * 1024 + row] = (v1 > v0) ? 1.0f : 0.0f;
        }
      }
    }
    // no sync needed: next GEMM reads xs[nxt] (read-read with logits phase);
    // gl rewrite is fenced by the post-gl-store sync of the next iteration
  }
}

extern "C" void kernel_launch(void* const* d_in, const int* in_sizes, int n_in,
                              void* d_out, int out_size, void* d_ws, size_t ws_size,
                              hipStream_t stream) {
  const float* x0 = (const float*)d_in[0];
  const float* x1 = (const float*)d_in[1];
  const float* x2 = (const float*)d_in[2];
  const float* gu = (const float*)d_in[4];
  const float* W0 = (const float*)d_in[5];
  const float* b0 = (const float*)d_in[6];
  const float* W1 = (const float*)d_in[7];
  const float* b1 = (const float*)d_in[8];
  const float* W_ih = (const float*)d_in[9];
  const float* W_hh = (const float*)d_in[10];
  const float* b_ih = (const float*)d_in[11];
  const float* b_hh = (const float*)d_in[12];
  const float* W_dec = (const float*)d_in[13];
  const float* b_dec = (const float*)d_in[14];
  float* outp = (float*)d_out;

  float* ws = (float*)d_ws;
  float* W4 = ws;                       // 384*1024 = 393216
  float* WTA = W4 + 393216;             // 304*64   = 19456
  float* WTB = WTA + 19456;             // 76*64    = 4864
  float* bias0 = WTB + 4864;            // 1024
  float* bias2 = bias0 + 1024;          // 1024
  float* reduced = bias2 + 1024;        // 128*1024*120 = 15728640

  k_prep<<<1635, 256, 0, stream>>>(W0, W1, W_ih, W_hh, W_dec, b_ih, b_hh, b_dec,
                                   W4, WTA, WTB, bias0, bias2);
  k_in<0><<<2048, 512, 0, stream>>>(x0, nullptr, WTA, b0, reduced);
  k_in<1><<<2048, 512, 0, stream>>>(x1, x2, WTB, b1, reduced);
  k_lstm<<<NBx, 1024, 0, stream>>>(reduced, W4, bias0, bias2, W_dec, b_dec, gu,
                                   outp);
}